// Round 3
// baseline (454.756 us; speedup 1.0000x reference)
//
#include <hip/hip_runtime.h>

#define N_ROWS 16384
#define DIM    4096
#define NE     64
#define NC     128   // gate cols | noise cols
#define TOPK   8
#define BM     32
#define BK     128
#define NKT    (DIM / BK)   // 32
#define NT     512

typedef _Float16 f16;
typedef _Float16 f16x8 __attribute__((ext_vector_type(8)));
typedef float    f32x4 __attribute__((ext_vector_type(4)));

#define LO_SCALE     2048.0f
#define INV_LO_SCALE (1.0f / 2048.0f)

// ---- prep: W[4096][64] x2 -> WT[128][4096] fp16 hi/lo (lo pre-scaled 2^11) ----
__global__ __launch_bounds__(256) void prep_wt(const float* __restrict__ Wg,
                                               const float* __restrict__ Wn,
                                               f16* __restrict__ WThi,
                                               f16* __restrict__ WTlo) {
    int gid = blockIdx.x * 256 + threadIdx.x;      // NC*DIM total
    int c = gid >> 12;                             // / DIM
    int k = gid & (DIM - 1);
    float v = (c < NE) ? Wg[(size_t)k * NE + c] : Wn[(size_t)k * NE + (c - NE)];
    f16 hi = (f16)v;
    f16 lo = (f16)((v - (float)hi) * LO_SCALE);
    WThi[gid] = hi;
    WTlo[gid] = lo;
}

// ---- main fused kernel: 512 thr, 8 waves x 16 cols, BM=32 ----
__global__ __launch_bounds__(NT, 4) void router_main(
    const float* __restrict__ x,
    const float* __restrict__ bg,
    const float* __restrict__ bn,
    const float* __restrict__ eps,
    const f16* __restrict__ WThi,
    const f16* __restrict__ WTlo,
    float* __restrict__ gates,
    float* __restrict__ logits)
{
    // A tiles in FRAG-MAJOR layout: [buf][rowblk][ks][lane][8elem] f16.
    // Fragment read = ds_read_b128 at lane*16 -> contiguous, conflict-free.
    __shared__ f16   Ah[2][2][4][64 * 8];   // 16 KB
    __shared__ f16   Al[2][2][4][64 * 8];   // 16 KB
    __shared__ float Lrow[BM][NC + 4];      // 16.9 KB, 16B-aligned rows

    const int tid  = threadIdx.x;
    const int lane = tid & 63;
    const int wid  = tid >> 6;        // 0..7 : wave owns 16 output cols, full K
    const int l15  = lane & 15;
    const int lk   = lane >> 4;       // 0..3
    const int row0 = blockIdx.x * BM;

    // ---- staging geometry: thread covers row=tid&31, k-octet o=tid>>5 ----
    const int sr  = tid & 31;         // source row in tile
    const int so  = tid >> 5;         // 0..15 : k-octet within BK=128
    const int sb  = sr >> 4;          // dest row-block
    const int sks = so >> 2;          // dest ks
    const int sl  = ((so & 3) << 4) + (sr & 15);   // dest lane in frag layout
    const float* xbase = x + (size_t)(row0 + sr) * DIM + so * 8;

    // ---- B pointers: col = wid*16 + l15, k-octet base = lk*8 ----
    const f16* bhp = WThi + (size_t)(wid * 16 + l15) * DIM + lk * 8;
    const f16* blp = WTlo + (size_t)(wid * 16 + l15) * DIM + lk * 8;

    // ---- prefetch epilogue operands early (hide their latency under K-loop) ----
    const float bgv = bg[lane];
    const float bnv = bn[lane];
    float ev[4];
    #pragma unroll
    for (int it = 0; it < 4; ++it)
        ev[it] = eps[(size_t)(row0 + wid * 4 + it) * NE + lane];

    f32x4 acch[2], accl[2];
    #pragma unroll
    for (int b = 0; b < 2; ++b) {
        acch[b] = (f32x4){0.f, 0.f, 0.f, 0.f};
        accl[b] = (f32x4){0.f, 0.f, 0.f, 0.f};
    }

    float4 v0, v1;   // x prefetch registers (one kt-tile per thread = 8 f32)

#define LOADX(kt_)                                                    \
    do {                                                              \
        v0 = *(const float4*)(xbase + (size_t)(kt_) * BK);            \
        v1 = *(const float4*)(xbase + (size_t)(kt_) * BK + 4);        \
    } while (0)

#define STAGE(pp)                                                     \
    do {                                                              \
        f16 h0 = (f16)v0.x, h1 = (f16)v0.y, h2 = (f16)v0.z, h3 = (f16)v0.w; \
        f16 h4 = (f16)v1.x, h5 = (f16)v1.y, h6 = (f16)v1.z, h7 = (f16)v1.w; \
        *(f16x8*)&Ah[pp][sb][sks][sl * 8] = (f16x8){h0,h1,h2,h3,h4,h5,h6,h7}; \
        *(f16x8*)&Al[pp][sb][sks][sl * 8] = (f16x8){                  \
            (f16)((v0.x - (float)h0) * LO_SCALE),                     \
            (f16)((v0.y - (float)h1) * LO_SCALE),                     \
            (f16)((v0.z - (float)h2) * LO_SCALE),                     \
            (f16)((v0.w - (float)h3) * LO_SCALE),                     \
            (f16)((v1.x - (float)h4) * LO_SCALE),                     \
            (f16)((v1.y - (float)h5) * LO_SCALE),                     \
            (f16)((v1.z - (float)h6) * LO_SCALE),                     \
            (f16)((v1.w - (float)h7) * LO_SCALE)};                    \
    } while (0)

    // prologue
    LOADX(0);
    STAGE(0);
    LOADX(1);
    __syncthreads();

    for (int kt = 0; kt < NKT; ++kt) {
        const int p = kt & 1;

        // B fragments for this kt: 8 x b128, issued first, stay in flight
        f16x8 bh[4], bl[4];
        #pragma unroll
        for (int ks = 0; ks < 4; ++ks) {
            bh[ks] = *(const f16x8*)(bhp + (size_t)kt * BK + ks * 32);
            bl[ks] = *(const f16x8*)(blp + (size_t)kt * BK + ks * 32);
        }

        // stage next tile (waits only on OLDER x loads), refill x prefetch
        if (kt + 1 < NKT) STAGE(p ^ 1);
        if (kt + 2 < NKT) LOADX(kt + 2);

        // A frags from LDS (contiguous, conflict-free) + MFMA
        #pragma unroll
        for (int ks = 0; ks < 4; ++ks) {
            #pragma unroll
            for (int b = 0; b < 2; ++b) {
                const f16x8 ah = *(const f16x8*)&Ah[p][b][ks][lane * 8];
                const f16x8 al = *(const f16x8*)&Al[p][b][ks][lane * 8];
                acch[b] = __builtin_amdgcn_mfma_f32_16x16x32_f16(ah, bh[ks], acch[b], 0, 0, 0);
                accl[b] = __builtin_amdgcn_mfma_f32_16x16x32_f16(ah, bl[ks], accl[b], 0, 0, 0);
                accl[b] = __builtin_amdgcn_mfma_f32_16x16x32_f16(al, bh[ks], accl[b], 0, 0, 0);
            }
        }
        __syncthreads();
    }

    // C/D layout (m89-verified): col = lane&15, row = (lane>>4)*4 + j
    #pragma unroll
    for (int b = 0; b < 2; ++b) {
        const int rr = b * 16 + (lk << 2);
        const int cc = wid * 16 + l15;
        #pragma unroll
        for (int j = 0; j < 4; ++j)
            Lrow[rr + j][cc] = acch[b][j] + accl[b][j] * INV_LO_SCALE;
    }
    __syncthreads();   // Lrow complete

    // ---- epilogue: wave wid owns rows wid*4 .. wid*4+3, lane = expert ----
    float lgv[4];
    #pragma unroll
    for (int it = 0; it < 4; ++it) {
        const int r  = wid * 4 + it;
        const float gl = Lrow[r][lane];
        const float nl = Lrow[r][NE + lane];
        const float z  = nl + bnv;
        const float sp = fmaxf(z, 0.0f) + log1pf(expf(-fabsf(z)));   // softplus
        lgv[it] = gl + bgv + ev[it] * (sp + 0.01f);
    }
    __syncthreads();                 // all reads of Lrow done before overwrite
    #pragma unroll
    for (int it = 0; it < 4; ++it)
        Lrow[wid * 4 + it][lane] = lgv[it];
    __syncthreads();                 // publish noisy logits

    #pragma unroll
    for (int it = 0; it < 4; ++it) {
        const int r    = wid * 4 + it;
        const int grow = row0 + r;
        const float lg = lgv[it];

        int cnt = 0;
        #pragma unroll
        for (int e4 = 0; e4 < NE / 4; ++e4) {
            const f32x4 q = *(const f32x4*)&Lrow[r][e4 * 4];   // broadcast b128
            #pragma unroll
            for (int j = 0; j < 4; ++j) {
                const int e = e4 * 4 + j;
                cnt += (q[j] > lg) | ((q[j] == lg) & (e < lane));  // lax.top_k tie-break
            }
        }

        float m = lg;
        #pragma unroll
        for (int off = 32; off; off >>= 1) m = fmaxf(m, __shfl_xor(m, off, 64));
        const float pv = (cnt < TOPK) ? expf(lg - m) : 0.0f;
        float sum = pv;
        #pragma unroll
        for (int off = 32; off; off >>= 1) sum += __shfl_xor(sum, off, 64);

        gates [(size_t)grow * NE + lane] = pv / sum;
        logits[(size_t)grow * NE + lane] = lg;
    }
}

extern "C" void kernel_launch(void* const* d_in, const int* in_sizes, int n_in,
                              void* d_out, int out_size, void* d_ws, size_t ws_size,
                              hipStream_t stream) {
    const float* x   = (const float*)d_in[0];
    const float* Wg  = (const float*)d_in[1];
    const float* bg  = (const float*)d_in[2];
    const float* Wn  = (const float*)d_in[3];
    const float* bn  = (const float*)d_in[4];
    const float* eps = (const float*)d_in[5];

    float* gates  = (float*)d_out;
    float* logits = (float*)d_out + (size_t)N_ROWS * NE;

    f16* WThi = (f16*)d_ws;
    f16* WTlo = WThi + (size_t)NC * DIM;

    prep_wt<<<(NC * DIM) / 256, 256, 0, stream>>>(Wg, Wn, WThi, WTlo);
    router_main<<<N_ROWS / BM, NT, 0, stream>>>(x, bg, bn, eps, WThi, WTlo, gates, logits);
}

// Round 9
// 442.147 us; speedup vs baseline: 1.0285x; 1.0285x over previous
//
#include <hip/hip_runtime.h>

#define N_ROWS 16384
#define DIM    4096
#define NE     64
#define NC     128   // gate cols | noise cols
#define TOPK   8
#define BM     32
#define BK     128
#define NKT    (DIM / BK)   // 32
#define NT     512
#define LSTR   (NC + 4)     // Lrow stride (floats)

typedef _Float16 f16;
typedef _Float16 f16x8 __attribute__((ext_vector_type(8)));
typedef float    f32x4 __attribute__((ext_vector_type(4)));

#define LO_SCALE     2048.0f
#define INV_LO_SCALE (1.0f / 2048.0f)

// ---- prep: W[4096][64] x2 -> WT[128][4096] fp16 hi/lo (lo pre-scaled 2^11) ----
__global__ __launch_bounds__(256) void prep_wt(const float* __restrict__ Wg,
                                               const float* __restrict__ Wn,
                                               f16* __restrict__ WThi,
                                               f16* __restrict__ WTlo) {
    int gid = blockIdx.x * 256 + threadIdx.x;      // NC*DIM total
    int c = gid >> 12;                             // / DIM
    int k = gid & (DIM - 1);
    float v = (c < NE) ? Wg[(size_t)k * NE + c] : Wn[(size_t)k * NE + (c - NE)];
    f16 hi = (f16)v;
    f16 lo = (f16)((v - (float)hi) * LO_SCALE);
    WThi[gid] = hi;
    WTlo[gid] = lo;
}

// async global->LDS, 16B per lane; LDS dest must be wave-uniform base (+lane*16 by HW)
__device__ __forceinline__ void gload16(const float* g, void* lds) {
    __builtin_amdgcn_global_load_lds((const __attribute__((address_space(1))) void*)g,
                                     (__attribute__((address_space(3))) void*)lds,
                                     16, 0, 0);
}

// split 8 f32 -> f16 hi + f16 lo = (v-hi_trunc)*2048  (plain casts; compiler
// emits v_cvt_f16_f32 + packs — do NOT hand-write cvt_pkrtz, wrong vec elt type)
__device__ __forceinline__ void split8(const f32x4 va, const f32x4 vb,
                                       f16x8* h, f16x8* l) {
    float v[8], hf[8];
    #pragma unroll
    for (int i = 0; i < 4; ++i) { v[i] = va[i]; v[4 + i] = vb[i]; }
    #pragma unroll
    for (int i = 0; i < 8; ++i)
        hf[i] = __uint_as_float(__float_as_uint(v[i]) & 0xFFFFE000u);  // trunc to f16 mantissa
    f16x8 hh, ll;
    #pragma unroll
    for (int i = 0; i < 8; ++i) {
        hh[i] = (f16)hf[i];                           // exact (13-bit mantissa fits)
        ll[i] = (f16)((v[i] - hf[i]) * LO_SCALE);     // residual, pre-scaled
    }
    *h = hh; *l = ll;
}

// ---- main fused kernel: 512 thr, 8 waves x 16 cols, BM=32, BK=128 ----
__global__ __launch_bounds__(NT, 4) void router_main(
    const float* __restrict__ x,
    const float* __restrict__ bg,
    const float* __restrict__ bn,
    const float* __restrict__ eps,
    const f16* __restrict__ WThi,
    const f16* __restrict__ WTlo,
    float* __restrict__ gates,
    float* __restrict__ logits)
{
    // one 64 KB blob, constant-offset carve; Lrow overlays XA/XB after the K-loop
    __shared__ __align__(16) char smem[65536];
    float* XA  = (float*)(smem);            // 16 KB f32 tile (32 x 128)
    float* XB  = (float*)(smem + 16384);    // 16 KB
    f16*   AhA = (f16*)(smem + 32768);      // 8 KB frag-layout hi
    f16*   AlA = (f16*)(smem + 40960);      // 8 KB lo
    f16*   AhB = (f16*)(smem + 49152);
    f16*   AlB = (f16*)(smem + 57344);
    float* Lr  = (float*)(smem);            // [BM][LSTR] post-loop

    const int tid  = threadIdx.x;
    const int lane = tid & 63;
    const int wid  = tid >> 6;        // 0..7 : wave owns 16 output cols, full K
    const int l15  = lane & 15;
    const int lk   = lane >> 4;       // 0..3
    const int row0 = blockIdx.x * BM;

    // ---- stage geometry: wave wid DMAs chunks {2*wid, 2*wid+1} (2 rows each) ----
    const int chunk = wid * 2;
    const int srow0 = chunk * 2 + (lane >> 5);           // rows 4*wid + {0,1}
    const int scol  = (lane & 31) * 4;
    const float* gsrc0 = x + (size_t)(row0 + srow0) * DIM + scol;
    const float* gsrc1 = gsrc0 + 2 * DIM;                // chunk+1 -> rows +2

#define STAGE(t_, Xd_)                                                      \
    do {                                                                    \
        gload16(gsrc0 + (size_t)(t_) * BK, (char*)(Xd_) + chunk * 1024);    \
        gload16(gsrc1 + (size_t)(t_) * BK, (char*)(Xd_) + chunk * 1024 + 1024); \
    } while (0)

    // ---- restage geometry: thread handles 8 consecutive f32 of the tile ----
    const int rr_   = tid >> 4;                   // row 0..31
    const int rdoff = tid * 32;                   // byte offset into X tile
    const int wroff = (((rr_ >> 4) * 4 + ((tid & 15) >> 2)) * 1024)   // plane
                    + (rr_ & 15) * 64 + (tid & 3) * 16;               // row, k-octet

#define RESTAGE(Xs_, Ah_, Al_)                                              \
    do {                                                                    \
        f32x4 va = *(const f32x4*)((const char*)(Xs_) + rdoff);             \
        f32x4 vb = *(const f32x4*)((const char*)(Xs_) + rdoff + 16);        \
        f16x8 h_, l_;                                                       \
        split8(va, vb, &h_, &l_);                                           \
        *(f16x8*)((char*)(Ah_) + wroff) = h_;                               \
        *(f16x8*)((char*)(Al_) + wroff) = l_;                               \
    } while (0)

    // ---- B pointers: col = wid*16 + l15, k-octet base = lk*8 ----
    const f16* bhp = WThi + (size_t)(wid * 16 + l15) * DIM + lk * 8;
    const f16* blp = WTlo + (size_t)(wid * 16 + l15) * DIM + lk * 8;

    // frag read byte offset within an Ah/Al tile (plane = (rb*4+ks)*1024)
    const int fragoff = l15 * 64 + lk * 16;

    // ---- epilogue operand prefetch ----
    const float bgv = bg[lane];
    const float bnv = bn[lane];
    float ev[4];
    #pragma unroll
    for (int it = 0; it < 4; ++it)
        ev[it] = eps[(size_t)(row0 + wid * 4 + it) * NE + lane];

    f32x4 acch[2], accl[2];
    #pragma unroll
    for (int b = 0; b < 2; ++b) {
        acch[b] = (f32x4){0.f, 0.f, 0.f, 0.f};
        accl[b] = (f32x4){0.f, 0.f, 0.f, 0.f};
    }

#define MFMA_PHASE(t_, Ah_, Al_)                                            \
    do {                                                                    \
        f16x8 bh[4], bl[4];                                                 \
        _Pragma("unroll")                                                   \
        for (int ks = 0; ks < 4; ++ks) {                                    \
            bh[ks] = *(const f16x8*)(bhp + (size_t)(t_) * BK + ks * 32);    \
            bl[ks] = *(const f16x8*)(blp + (size_t)(t_) * BK + ks * 32);    \
        }                                                                   \
        _Pragma("unroll")                                                   \
        for (int ks = 0; ks < 4; ++ks)                                      \
            _Pragma("unroll")                                               \
            for (int b = 0; b < 2; ++b) {                                   \
                const f16x8 ah = *(const f16x8*)((const char*)(Ah_) + (b*4+ks)*1024 + fragoff); \
                const f16x8 al = *(const f16x8*)((const char*)(Al_) + (b*4+ks)*1024 + fragoff); \
                acch[b] = __builtin_amdgcn_mfma_f32_16x16x32_f16(ah, bh[ks], acch[b], 0, 0, 0); \
                accl[b] = __builtin_amdgcn_mfma_f32_16x16x32_f16(ah, bl[ks], accl[b], 0, 0, 0); \
                accl[b] = __builtin_amdgcn_mfma_f32_16x16x32_f16(al, bh[ks], accl[b], 0, 0, 0); \
            }                                                               \
    } while (0)

    // ---- pipeline prologue ----
    STAGE(0, XA);
    __syncthreads();                 // vmcnt drain: XA(tile0) ready
    RESTAGE(XA, AhA, AlA);
    STAGE(1, XB);
    __syncthreads();                 // AhA ready; XB(tile1) ready

    // ---- main loop: phase t = {B(t) | stage(t+2) | restage(t+1) | MFMA(t)} ----
    for (int t = 0; t < NKT; t += 2) {
        {   // even phase: cur=A, next=B, stage->XA
            if (t + 2 < NKT) STAGE(t + 2, XA);
            if (t + 1 < NKT) RESTAGE(XB, AhB, AlB);
            MFMA_PHASE(t, AhA, AlA);
            __syncthreads();
        }
        {   // odd phase: cur=B, next=A, stage->XB
            if (t + 3 < NKT) STAGE(t + 3, XB);
            if (t + 2 < NKT) RESTAGE(XA, AhA, AlA);
            MFMA_PHASE(t + 1, AhB, AlB);
            __syncthreads();
        }
    }

    // ---- C write: col = lane&15, row = (lane>>4)*4 + j (m89-verified) ----
    #pragma unroll
    for (int b = 0; b < 2; ++b) {
        const int rr = b * 16 + (lk << 2);
        const int cc = wid * 16 + l15;
        #pragma unroll
        for (int j = 0; j < 4; ++j)
            Lr[(rr + j) * LSTR + cc] = acch[b][j] + accl[b][j] * INV_LO_SCALE;
    }
    __syncthreads();   // Lrow complete

    // ---- epilogue: wave wid owns rows wid*4..wid*4+3, lane = expert ----
    float lgv[4];
    #pragma unroll
    for (int it = 0; it < 4; ++it) {
        const int r  = wid * 4 + it;
        const float gl = Lr[r * LSTR + lane];
        const float nl = Lr[r * LSTR + NE + lane];
        const float z  = nl + bnv;
        const float sp = fmaxf(z, 0.0f) + log1pf(expf(-fabsf(z)));   // softplus
        lgv[it] = gl + bgv + ev[it] * (sp + 0.01f);
    }
    __syncthreads();                 // all reads done before overwrite
    #pragma unroll
    for (int it = 0; it < 4; ++it)
        Lr[(wid * 4 + it) * LSTR + lane] = lgv[it];
    __syncthreads();                 // publish noisy logits

    #pragma unroll
    for (int it = 0; it < 4; ++it) {
        const int r    = wid * 4 + it;
        const int grow = row0 + r;
        const float lg = lgv[it];

        int cnt = 0;
        #pragma unroll
        for (int e4 = 0; e4 < NE / 4; ++e4) {
            const f32x4 q = *(const f32x4*)&Lr[r * LSTR + e4 * 4];
            #pragma unroll
            for (int j = 0; j < 4; ++j) {
                const int e = e4 * 4 + j;
                cnt += (q[j] > lg) | ((q[j] == lg) & (e < lane));  // lax.top_k tie-break
            }
        }

        float m = lg;
        #pragma unroll
        for (int off = 32; off; off >>= 1) m = fmaxf(m, __shfl_xor(m, off, 64));
        const float pv = (cnt < TOPK) ? expf(lg - m) : 0.0f;
        float sum = pv;
        #pragma unroll
        for (int off = 32; off; off >>= 1) sum += __shfl_xor(sum, off, 64);

        gates [(size_t)grow * NE + lane] = pv / sum;
        logits[(size_t)grow * NE + lane] = lg;
    }
}

extern "C" void kernel_launch(void* const* d_in, const int* in_sizes, int n_in,
                              void* d_out, int out_size, void* d_ws, size_t ws_size,
                              hipStream_t stream) {
    const float* x   = (const float*)d_in[0];
    const float* Wg  = (const float*)d_in[1];
    const float* bg  = (const float*)d_in[2];
    const float* Wn  = (const float*)d_in[3];
    const float* bn  = (const float*)d_in[4];
    const float* eps = (const float*)d_in[5];

    float* gates  = (float*)d_out;
    float* logits = (float*)d_out + (size_t)N_ROWS * NE;

    f16* WThi = (f16*)d_ws;
    f16* WTlo = WThi + (size_t)NC * DIM;

    prep_wt<<<(NC * DIM) / 256, 256, 0, stream>>>(Wg, Wn, WThi, WTlo);
    router_main<<<N_ROWS / BM, NT, 0, stream>>>(x, bg, bn, eps, WThi, WTlo, gates, logits);
}